// Round 5
// baseline (444.839 us; speedup 1.0000x reference)
//
#include <hip/hip_runtime.h>
#include <hip/hip_bf16.h>

typedef __attribute__((ext_vector_type(8))) short bf16x8;
typedef __attribute__((ext_vector_type(4))) float f32x4;

typedef const __attribute__((address_space(1))) void gv_t;
typedef __attribute__((address_space(3))) void lv_t;
#define GLL16(g, l) __builtin_amdgcn_global_load_lds((gv_t*)(g), (lv_t*)(l), 16, 0, 0)

__device__ __forceinline__ short f2bf(float f) {
    __hip_bfloat16 h = __float2bfloat16(f);
    return *reinterpret_cast<short*>(&h);
}

__device__ __forceinline__ float wred(float v) {
    #pragma unroll
    for (int m = 1; m < 64; m <<= 1) v += __shfl_xor(v, m);
    return v;
}

// ---------------- fp32 -> bf16 convert (weights) ----------------
__global__ __launch_bounds__(256) void cvt_kernel(const float* __restrict__ in,
                                                  short* __restrict__ out, int n4) {
    int i = blockIdx.x * 256 + threadIdx.x;
    if (i < n4) {
        float4 v = ((const float4*)in)[i];
        short4 o;
        o.x = f2bf(v.x); o.y = f2bf(v.y); o.z = f2bf(v.z); o.w = f2bf(v.w);
        ((short4*)out)[i] = o;
    }
}

// ---------------- LayerNorm (fp32 in, bf16 out), row = 1024 ----------------
__global__ __launch_bounds__(256) void ln_kernel(const float* __restrict__ x,
                                                 const float* __restrict__ g,
                                                 short* __restrict__ y) {
    const int row = blockIdx.x, tid = threadIdx.x;
    const float4 v = ((const float4*)(x + (size_t)row * 1024))[tid];
    float s = v.x + v.y + v.z + v.w;
    float s2 = v.x * v.x + v.y * v.y + v.z * v.z + v.w * v.w;
    #pragma unroll
    for (int m = 1; m < 64; m <<= 1) { s += __shfl_xor(s, m); s2 += __shfl_xor(s2, m); }
    __shared__ float rs[4], rs2[4];
    if ((tid & 63) == 0) { rs[tid >> 6] = s; rs2[tid >> 6] = s2; }
    __syncthreads();
    s = rs[0] + rs[1] + rs[2] + rs[3];
    s2 = rs2[0] + rs2[1] + rs2[2] + rs2[3];
    const float mean = s * (1.0f / 1024.0f);
    const float var = s2 * (1.0f / 1024.0f) - mean * mean;
    const float r = rsqrtf(var + 1e-5f);
    const float4 gg = ((const float4*)g)[tid];
    short4 o;
    o.x = f2bf((v.x - mean) * r * gg.x);
    o.y = f2bf((v.y - mean) * r * gg.y);
    o.z = f2bf((v.z - mean) * r * gg.z);
    o.w = f2bf((v.w - mean) * r * gg.w);
    ((short4*)y)[(size_t)row * 256 + tid] = o;
}

// ---------------- GEMM: C[M,N] = A[M,K] * B[N,K]^T, bf16 in, templated epilogue ----
// EPI 0: QKV split -> q[b,h,t,d] (pre-scaled by 1/8), k[b,h,t,d], vT[b,h,d,t] (bf16)
// EPI 1: fp32 row-major
// EPI 2: exact GELU -> bf16 row-major
template <int EPI>
__global__ __launch_bounds__(256, 2) void gemm_bt(const short* __restrict__ A,
                                                  const short* __restrict__ Bw,
                                                  int M, int N, int K,
                                                  void* __restrict__ o0,
                                                  void* __restrict__ o1,
                                                  void* __restrict__ o2) {
    __shared__ __align__(16) short As[128 * 32];
    __shared__ __align__(16) short Bs[128 * 32];
    const int tid = threadIdx.x;
    const int wid = tid >> 6, lane = tid & 63;
    const int wm = wid >> 1, wn = wid & 1;
    const int col = lane & 15, grp = lane >> 4;
    const int m0 = blockIdx.x * 128, n0 = blockIdx.y * 128;
    f32x4 acc[4][4] = {};
    const int rowA = tid >> 2;
    const int kc = (tid & 3) * 8;
    const short* ga = A + (size_t)(m0 + rowA) * K + kc;
    const short* gb = Bw + (size_t)(n0 + rowA) * K + kc;
    short* lA = As + wid * 512;
    short* lB = Bs + wid * 512;
    for (int k0 = 0; k0 < K; k0 += 32) {
        GLL16(ga + k0, lA);
        GLL16(ga + k0 + (size_t)64 * K, lA + 2048);
        GLL16(gb + k0, lB);
        GLL16(gb + k0 + (size_t)64 * K, lB + 2048);
        __syncthreads();
        bf16x8 af[4], bfr[4];
        #pragma unroll
        for (int i = 0; i < 4; ++i) {
            af[i] = *(const bf16x8*)&As[(wm * 64 + i * 16 + col) * 32 + grp * 8];
            bfr[i] = *(const bf16x8*)&Bs[(wn * 64 + i * 16 + col) * 32 + grp * 8];
        }
        #pragma unroll
        for (int mi = 0; mi < 4; ++mi)
            #pragma unroll
            for (int ni = 0; ni < 4; ++ni)
                acc[mi][ni] = __builtin_amdgcn_mfma_f32_16x16x32_bf16(af[mi], bfr[ni], acc[mi][ni], 0, 0, 0);
        __syncthreads();
    }
    #pragma unroll
    for (int mi = 0; mi < 4; ++mi) {
        #pragma unroll
        for (int ni = 0; ni < 4; ++ni) {
            #pragma unroll
            for (int i = 0; i < 4; ++i) {
                const int m = m0 + wm * 64 + mi * 16 + grp * 4 + i;
                const int n = n0 + wn * 64 + ni * 16 + col;
                const float v = acc[mi][ni][i];
                if (EPI == 0) {
                    const int b = m >> 11, t = m & 2047;
                    const int which = n >> 10, nn = n & 1023;
                    const int h = nn >> 6, d = nn & 63;
                    const size_t bh = (size_t)(b * 16 + h);
                    if (which == 0)
                        ((short*)o0)[(bh * 2048 + t) * 64 + d] = f2bf(v * 0.125f);
                    else if (which == 1)
                        ((short*)o1)[(bh * 2048 + t) * 64 + d] = f2bf(v);
                    else
                        ((short*)o2)[(bh * 64 + d) * 2048 + t] = f2bf(v);
                } else if (EPI == 1) {
                    ((float*)o0)[(size_t)m * N + n] = v;
                } else {
                    const float gl = 0.5f * v * (1.0f + erff(v * 0.70710678118654752f));
                    ((short*)o0)[(size_t)m * N + n] = f2bf(gl);
                }
            }
        }
    }
}

// ---------------- Flash attention, causal, swapped-QK + k-split --------------------
// Q (pre-scaled),K:[b,h,t,d]  VT:[b,h,d,t]  bf16.  One block = 16 q-rows; 4 waves
// split the k-tiles (64 wide) round-robin.  PV computed as O^T = V^T * P so the
// rescale factor is lane-local.  Grid swizzled so ALL blocks of one bh land on one
// XCD (id%8 round-robin): per-bh K+V = 512KB stays L2-resident -> kills HBM refetch.
__global__ __launch_bounds__(256, 8) void attn_kernel(const short* __restrict__ Q,
                                                      const short* __restrict__ Kg,
                                                      const short* __restrict__ VT,
                                                      short* __restrict__ Y) {
    __shared__ float mLds[4][16], lLds[4][16];
    __shared__ __align__(16) char uLds[4][4352];  // union: P short[16][72] | O^T float[64][17]
    // XCD-affinity swizzle: 4096 blocks; xcd = id&7 gets bh in {4*xcd..4*xcd+3}
    const int id = blockIdx.x + (blockIdx.y << 7);
    const int rest = id >> 3;
    const int bh = (id & 7) * 4 + (rest >> 7);
    const int j = 127 - (rest & 127);  // q-strip, biggest workload first per XCD
    const int tid = threadIdx.x, wid = tid >> 6, lane = tid & 63;
    const int ql = lane & 15, g = lane >> 4;
    const int q0 = j * 16;
    const int lt = j >> 2;            // last k-tile index (diagonal)
    const short* Qb = Q + (size_t)bh * 2048 * 64;
    const short* Kb = Kg + (size_t)bh * 2048 * 64;
    const short* Vb = VT + (size_t)bh * 64 * 2048;
    short* Pw = (short*)uLds[wid];
    bf16x8 qf[2];
    qf[0] = *(const bf16x8*)&Qb[(size_t)(q0 + ql) * 64 + 8 * g];
    qf[1] = *(const bf16x8*)&Qb[(size_t)(q0 + ql) * 64 + 32 + 8 * g];
    f32x4 o[4] = {};                  // o[nf][r] = O^T[d=16nf+4g+r][q=ql]
    float m = -1e30f, lsum = 0.0f;
    for (int kt = wid; kt <= lt; kt += 4) {
        const int kbase = kt * 64;
        // S^T[k][q]: lane (ql,g) -> s[kb][r] = S[kbase+16kb+4g+r][q0+ql]
        f32x4 s[4];
        #pragma unroll
        for (int kb = 0; kb < 4; ++kb) {
            bf16x8 k0 = *(const bf16x8*)&Kb[(size_t)(kbase + 16 * kb + ql) * 64 + 8 * g];
            bf16x8 k1 = *(const bf16x8*)&Kb[(size_t)(kbase + 16 * kb + ql) * 64 + 32 + 8 * g];
            f32x4 z = {0.f, 0.f, 0.f, 0.f};
            z = __builtin_amdgcn_mfma_f32_16x16x32_bf16(k0, qf[0], z, 0, 0, 0);
            z = __builtin_amdgcn_mfma_f32_16x16x32_bf16(k1, qf[1], z, 0, 0, 0);
            s[kb] = z;
        }
        if (kt == lt) {  // causal mask on the diagonal tile
            #pragma unroll
            for (int kb = 0; kb < 4; ++kb)
                #pragma unroll
                for (int r = 0; r < 4; ++r)
                    if (kbase + 16 * kb + 4 * g + r > q0 + ql) s[kb][r] = -1e30f;
        }
        // row max over k for q=ql: register tree + 2 shfl
        float t0 = fmaxf(fmaxf(s[0][0], s[0][1]), fmaxf(s[0][2], s[0][3]));
        float t1 = fmaxf(fmaxf(s[1][0], s[1][1]), fmaxf(s[1][2], s[1][3]));
        float t2 = fmaxf(fmaxf(s[2][0], s[2][1]), fmaxf(s[2][2], s[2][3]));
        float t3 = fmaxf(fmaxf(s[3][0], s[3][1]), fmaxf(s[3][2], s[3][3]));
        float tmax = fmaxf(fmaxf(t0, t1), fmaxf(t2, t3));
        tmax = fmaxf(tmax, __shfl_xor(tmax, 16));
        tmax = fmaxf(tmax, __shfl_xor(tmax, 32));
        const float mnew = fmaxf(m, tmax);
        const float sc = __expf(m - mnew);
        m = mnew;
        float rsum = 0.0f;
        #pragma unroll
        for (int kb = 0; kb < 4; ++kb) {
            const float e0 = __expf(s[kb][0] - mnew);
            const float e1 = __expf(s[kb][1] - mnew);
            const float e2 = __expf(s[kb][2] - mnew);
            const float e3 = __expf(s[kb][3] - mnew);
            rsum += (e0 + e1) + (e2 + e3);
            short4 pk;
            pk.x = f2bf(e0); pk.y = f2bf(e1); pk.z = f2bf(e2); pk.w = f2bf(e3);
            *(short4*)&Pw[ql * 72 + 16 * kb + 4 * g] = pk;
        }
        rsum += __shfl_xor(rsum, 16);
        rsum += __shfl_xor(rsum, 32);
        lsum = lsum * sc + rsum;
        // rescale O^T: column q=ql -> this lane's own sc, no broadcast
        #pragma unroll
        for (int nf = 0; nf < 4; ++nf)
            #pragma unroll
            for (int r = 0; r < 4; ++r) o[nf][r] *= sc;
        // O^T += V^T * P : A = V^T frags (16B loads), B = P frags from LDS
        const bf16x8 pb0 = *(const bf16x8*)&Pw[ql * 72 + 8 * g];
        const bf16x8 pb1 = *(const bf16x8*)&Pw[ql * 72 + 32 + 8 * g];
        #pragma unroll
        for (int nf = 0; nf < 4; ++nf) {
            bf16x8 v0 = *(const bf16x8*)&Vb[(size_t)(nf * 16 + ql) * 2048 + kbase + 8 * g];
            bf16x8 v1 = *(const bf16x8*)&Vb[(size_t)(nf * 16 + ql) * 2048 + kbase + 32 + 8 * g];
            o[nf] = __builtin_amdgcn_mfma_f32_16x16x32_bf16(v0, pb0, o[nf], 0, 0, 0);
            o[nf] = __builtin_amdgcn_mfma_f32_16x16x32_bf16(v1, pb1, o[nf], 0, 0, 0);
        }
    }
    // publish partials (per-wave region of the union buffer; P is dead now)
    if (g == 0) { mLds[wid][ql] = m; lLds[wid][ql] = lsum; }
    float* Ow = (float*)uLds[wid];    // [64][17]
    #pragma unroll
    for (int nf = 0; nf < 4; ++nf)
        #pragma unroll
        for (int r = 0; r < 4; ++r)
            Ow[(16 * nf + 4 * g + r) * 17 + ql] = o[nf][r];
    __syncthreads();
    // combine across the 4 k-split partials; thread (wid,lane): d=lane, q=4*wid+r
    const int b = bh >> 4, h = bh & 15;
    #pragma unroll
    for (int r = 0; r < 4; ++r) {
        const int q = wid * 4 + r;
        const float m0 = mLds[0][q], m1 = mLds[1][q], m2 = mLds[2][q], m3 = mLds[3][q];
        const float M = fmaxf(fmaxf(m0, m1), fmaxf(m2, m3));
        const float e0 = __expf(m0 - M), e1 = __expf(m1 - M);
        const float e2 = __expf(m2 - M), e3 = __expf(m3 - M);
        const float L = lLds[0][q] * e0 + lLds[1][q] * e1 + lLds[2][q] * e2 + lLds[3][q] * e3;
        const float Ov = ((float*)uLds[0])[lane * 17 + q] * e0 +
                         ((float*)uLds[1])[lane * 17 + q] * e1 +
                         ((float*)uLds[2])[lane * 17 + q] * e2 +
                         ((float*)uLds[3])[lane * 17 + q] * e3;
        Y[((size_t)b * 2048 + q0 + q) * 1024 + h * 64 + lane] = f2bf(Ov / L);
    }
}

// ---------------- Hyperbolic residual: out = expmap(x, v, c), per-head wave ------
__global__ __launch_bounds__(256) void expmap_kernel(const float* __restrict__ x,
                                                     const float* __restrict__ v,
                                                     const float* __restrict__ carr,
                                                     float* __restrict__ out) {
    const int blk = blockIdx.x;
    const int row = blk >> 2;
    const int head = (blk & 3) * 4 + (threadIdx.x >> 6);
    const int lane = threadIdx.x & 63;
    const size_t idx = (size_t)row * 1024 + head * 64 + lane;
    float c = carr[head];
    c = fminf(fmaxf(c, 1e-4f), 1.0f);
    const float xe = x[idx], ve = v[idx];
    const float xn = wred(xe * xe);
    const float vns = wred(ve * ve);
    const float vn = sqrtf(vns + 1e-9f);
    const float sf = 2.0f / (1.0f + c * xn + 1e-9f);
    const float targ = fabsf(0.5f * c * sf * vns);
    const float coeff = (1.0f / (sqrtf(c + 1e-9f) + 1e-9f)) * tanhf(sqrtf(targ + 1e-9f));
    const float ye = coeff * ve / (vn + 1e-9f);
    const float yn = wred(ye * ye);
    const float ip = wred(xe * ye);
    const float num = (1.0f + 2.0f * c * ip + c * yn) * xe + (1.0f - c * xn) * ye;
    const float den = 1.0f + 2.0f * c * ip + c * c * xn * yn;
    out[idx] = num / (den + 1e-9f);
}

extern "C" void kernel_launch(void* const* d_in, const int* in_sizes, int n_in,
                              void* d_out, int out_size, void* d_ws, size_t ws_size,
                              hipStream_t stream) {
    (void)in_sizes; (void)n_in; (void)out_size; (void)ws_size;
    const float* x      = (const float*)d_in[0];
    const float* ln1_g  = (const float*)d_in[1];
    const float* w_qkv  = (const float*)d_in[2];
    const float* w_proj = (const float*)d_in[3];
    const float* c_attn = (const float*)d_in[4];
    const float* ln2_g  = (const float*)d_in[5];
    const float* w_fc   = (const float*)d_in[6];
    const float* w_mlp  = (const float*)d_in[7];
    const float* c_mlp  = (const float*)d_in[8];
    float* out = (float*)d_out;
    char* ws = (char*)d_ws;
    const size_t MB = 1024 * 1024;

    short* wqkv_bf  = (short*)(ws + 0 * MB);    // 6 MB
    short* wproj_bf = (short*)(ws + 6 * MB);    // 2 MB
    short* wfc_bf   = (short*)(ws + 8 * MB);    // 8 MB
    short* wmlp_bf  = (short*)(ws + 16 * MB);   // 8 MB
    short* y_bf     = (short*)(ws + 24 * MB);   // 8 MB (LN1 out; reused for LN2 out)
    short* q_bf     = (short*)(ws + 32 * MB);   // 8 MB
    short* k_bf     = (short*)(ws + 40 * MB);   // 8 MB
    short* vT_bf    = (short*)(ws + 48 * MB);   // 8 MB
    short* att_bf   = (short*)(ws + 56 * MB);   // 8 MB
    float* a_f32    = (float*)(ws + 64 * MB);   // 16 MB
    float* x1       = (float*)(ws + 80 * MB);   // 16 MB
    short* g_bf     = (short*)(ws + 32 * MB);   // 32 MB (reuses q/k/vT/att)
    float* h_f32    = (float*)(ws + 64 * MB);   // 16 MB (reuses a)

    cvt_kernel<<<3072, 256, 0, stream>>>(w_qkv, wqkv_bf, 3072 * 1024 / 4);
    cvt_kernel<<<1024, 256, 0, stream>>>(w_proj, wproj_bf, 1024 * 1024 / 4);
    cvt_kernel<<<4096, 256, 0, stream>>>(w_fc, wfc_bf, 4096 * 1024 / 4);
    cvt_kernel<<<4096, 256, 0, stream>>>(w_mlp, wmlp_bf, 1024 * 4096 / 4);

    ln_kernel<<<4096, 256, 0, stream>>>(x, ln1_g, y_bf);
    gemm_bt<0><<<dim3(32, 24), 256, 0, stream>>>(y_bf, wqkv_bf, 4096, 3072, 1024,
                                                 q_bf, k_bf, vT_bf);
    attn_kernel<<<dim3(128, 32), 256, 0, stream>>>(q_bf, k_bf, vT_bf, att_bf);
    gemm_bt<1><<<dim3(32, 8), 256, 0, stream>>>(att_bf, wproj_bf, 4096, 1024, 1024,
                                                a_f32, nullptr, nullptr);
    expmap_kernel<<<16384, 256, 0, stream>>>(x, a_f32, c_attn, x1);
    ln_kernel<<<4096, 256, 0, stream>>>(x1, ln2_g, y_bf);
    gemm_bt<2><<<dim3(32, 32), 256, 0, stream>>>(y_bf, wfc_bf, 4096, 4096, 1024,
                                                 g_bf, nullptr, nullptr);
    gemm_bt<1><<<dim3(32, 8), 256, 0, stream>>>(g_bf, wmlp_bf, 4096, 1024, 4096,
                                                h_f32, nullptr, nullptr);
    expmap_kernel<<<16384, 256, 0, stream>>>(x1, h_f32, c_mlp, out);
}

// Round 7
// 333.824 us; speedup vs baseline: 1.3326x; 1.3326x over previous
//
#include <hip/hip_runtime.h>
#include <hip/hip_bf16.h>

typedef __attribute__((ext_vector_type(8))) short bf16x8;
typedef __attribute__((ext_vector_type(4))) float f32x4;

typedef const __attribute__((address_space(1))) void gv_t;
typedef __attribute__((address_space(3))) void lv_t;
#define GLL16(g, l) __builtin_amdgcn_global_load_lds((gv_t*)(g), (lv_t*)(l), 16, 0, 0)

__device__ __forceinline__ short f2bf(float f) {
    __hip_bfloat16 h = __float2bfloat16(f);
    return *reinterpret_cast<short*>(&h);
}

__device__ __forceinline__ float wred(float v) {
    #pragma unroll
    for (int m = 1; m < 64; m <<= 1) v += __shfl_xor(v, m);
    return v;
}

// ---------------- fp32 -> bf16 convert (weights) ----------------
__global__ __launch_bounds__(256) void cvt_kernel(const float* __restrict__ in,
                                                  short* __restrict__ out, int n4) {
    int i = blockIdx.x * 256 + threadIdx.x;
    if (i < n4) {
        float4 v = ((const float4*)in)[i];
        short4 o;
        o.x = f2bf(v.x); o.y = f2bf(v.y); o.z = f2bf(v.z); o.w = f2bf(v.w);
        ((short4*)out)[i] = o;
    }
}

// ---------------- LayerNorm (fp32 in, bf16 out), row = 1024 ----------------
__global__ __launch_bounds__(256) void ln_kernel(const float* __restrict__ x,
                                                 const float* __restrict__ g,
                                                 short* __restrict__ y) {
    const int row = blockIdx.x, tid = threadIdx.x;
    const float4 v = ((const float4*)(x + (size_t)row * 1024))[tid];
    float s = v.x + v.y + v.z + v.w;
    float s2 = v.x * v.x + v.y * v.y + v.z * v.z + v.w * v.w;
    #pragma unroll
    for (int m = 1; m < 64; m <<= 1) { s += __shfl_xor(s, m); s2 += __shfl_xor(s2, m); }
    __shared__ float rs[4], rs2[4];
    if ((tid & 63) == 0) { rs[tid >> 6] = s; rs2[tid >> 6] = s2; }
    __syncthreads();
    s = rs[0] + rs[1] + rs[2] + rs[3];
    s2 = rs2[0] + rs2[1] + rs2[2] + rs2[3];
    const float mean = s * (1.0f / 1024.0f);
    const float var = s2 * (1.0f / 1024.0f) - mean * mean;
    const float r = rsqrtf(var + 1e-5f);
    const float4 gg = ((const float4*)g)[tid];
    short4 o;
    o.x = f2bf((v.x - mean) * r * gg.x);
    o.y = f2bf((v.y - mean) * r * gg.y);
    o.z = f2bf((v.z - mean) * r * gg.z);
    o.w = f2bf((v.w - mean) * r * gg.w);
    ((short4*)y)[(size_t)row * 256 + tid] = o;
}

// ---------------- GEMM: C[M,N] = A[M,K] * B[N,K]^T, bf16 in, templated epilogue ----
// EPI 0: QKV split -> q[b,h,t,d] (pre-scaled by 1/8), k[b,h,t,d], vT[b,h,d,t] (bf16)
// EPI 1: fp32 row-major
// EPI 2: exact GELU -> bf16 row-major
template <int EPI>
__global__ __launch_bounds__(256, 2) void gemm_bt(const short* __restrict__ A,
                                                  const short* __restrict__ Bw,
                                                  int M, int N, int K,
                                                  void* __restrict__ o0,
                                                  void* __restrict__ o1,
                                                  void* __restrict__ o2) {
    __shared__ __align__(16) short As[128 * 32];
    __shared__ __align__(16) short Bs[128 * 32];
    const int tid = threadIdx.x;
    const int wid = tid >> 6, lane = tid & 63;
    const int wm = wid >> 1, wn = wid & 1;
    const int col = lane & 15, grp = lane >> 4;
    const int m0 = blockIdx.x * 128, n0 = blockIdx.y * 128;
    f32x4 acc[4][4] = {};
    const int rowA = tid >> 2;
    const int kc = (tid & 3) * 8;
    const short* ga = A + (size_t)(m0 + rowA) * K + kc;
    const short* gb = Bw + (size_t)(n0 + rowA) * K + kc;
    short* lA = As + wid * 512;
    short* lB = Bs + wid * 512;
    for (int k0 = 0; k0 < K; k0 += 32) {
        GLL16(ga + k0, lA);
        GLL16(ga + k0 + (size_t)64 * K, lA + 2048);
        GLL16(gb + k0, lB);
        GLL16(gb + k0 + (size_t)64 * K, lB + 2048);
        __syncthreads();
        bf16x8 af[4], bfr[4];
        #pragma unroll
        for (int i = 0; i < 4; ++i) {
            af[i] = *(const bf16x8*)&As[(wm * 64 + i * 16 + col) * 32 + grp * 8];
            bfr[i] = *(const bf16x8*)&Bs[(wn * 64 + i * 16 + col) * 32 + grp * 8];
        }
        #pragma unroll
        for (int mi = 0; mi < 4; ++mi)
            #pragma unroll
            for (int ni = 0; ni < 4; ++ni)
                acc[mi][ni] = __builtin_amdgcn_mfma_f32_16x16x32_bf16(af[mi], bfr[ni], acc[mi][ni], 0, 0, 0);
        __syncthreads();
    }
    #pragma unroll
    for (int mi = 0; mi < 4; ++mi) {
        #pragma unroll
        for (int ni = 0; ni < 4; ++ni) {
            #pragma unroll
            for (int i = 0; i < 4; ++i) {
                const int m = m0 + wm * 64 + mi * 16 + grp * 4 + i;
                const int n = n0 + wn * 64 + ni * 16 + col;
                const float v = acc[mi][ni][i];
                if (EPI == 0) {
                    const int b = m >> 11, t = m & 2047;
                    const int which = n >> 10, nn = n & 1023;
                    const int h = nn >> 6, d = nn & 63;
                    const size_t bh = (size_t)(b * 16 + h);
                    if (which == 0)
                        ((short*)o0)[(bh * 2048 + t) * 64 + d] = f2bf(v * 0.125f);
                    else if (which == 1)
                        ((short*)o1)[(bh * 2048 + t) * 64 + d] = f2bf(v);
                    else
                        ((short*)o2)[(bh * 64 + d) * 2048 + t] = f2bf(v);
                } else if (EPI == 1) {
                    ((float*)o0)[(size_t)m * N + n] = v;
                } else {
                    const float gl = 0.5f * v * (1.0f + erff(v * 0.70710678118654752f));
                    ((short*)o0)[(size_t)m * N + n] = f2bf(gl);
                }
            }
        }
    }
}

// ---------------- Flash attention, causal, LDS-staged K/V, 128-row q-tile ---------
// Q (pre-scaled),K:[b,h,t,d]  VT:[b,h,d,t]  bf16.
// Block = 128 q-rows, 4 waves x 32 rows (2 strips of 16). K-tile [64][64] and
// V^T-tile [64][64] double-buffered in LDS via global_load_lds (XOR slot swizzle
// baked into the GLOBAL source address; same XOR on the ds_read side).
// Swapped QK^T (S^T) + O^T = V^T*P keep softmax/rescale lane-local.
__global__ __launch_bounds__(256, 3) void attn_kernel(const short* __restrict__ Q,
                                                      const short* __restrict__ Kg,
                                                      const short* __restrict__ VT,
                                                      short* __restrict__ Y) {
    __shared__ __align__(16) short Ks[2][4096];   // [buf][64 rows][64] swizzled, 8KB each
    __shared__ __align__(16) short Vs[2][4096];
    __shared__ __align__(16) short Plds[4][16 * 72];
    const int j = 15 - blockIdx.x;    // q-block, biggest workload first
    const int bh = blockIdx.y;
    const int tid = threadIdx.x, wid = tid >> 6, lane = tid & 63;
    const int ql = lane & 15, g = lane >> 4;
    const int r8 = lane >> 3, s8 = lane & 7;
    const int q0w = j * 128 + wid * 32;
    const int lt = 2 * j + 1;         // last k-tile index
    const short* Qb = Q + (size_t)bh * 2048 * 64;
    const short* Kb = Kg + (size_t)bh * 2048 * 64;
    const short* Vb = VT + (size_t)bh * 64 * 2048;
    short* Pw = &Plds[wid][0];

    // Q fragments for both strips (B-operand: col=ql -> q-row q0s+ql)
    bf16x8 qf[2][2];
    #pragma unroll
    for (int qs = 0; qs < 2; ++qs) {
        qf[qs][0] = *(const bf16x8*)&Qb[(size_t)(q0w + 16 * qs + ql) * 64 + 8 * g];
        qf[qs][1] = *(const bf16x8*)&Qb[(size_t)(q0w + 16 * qs + ql) * 64 + 32 + 8 * g];
    }
    f32x4 o[2][4] = {};               // o[qs][nf][r] = O^T[d=16nf+4g+r][q=ql]
    float m[2] = {-1e30f, -1e30f}, lsum[2] = {0.f, 0.f};

    // stage tile kt into buffer b_: K rows [64][64], V^T rows [64][64]; slot^row&7
#define STAGE(b_, kt_) do {                                                      \
        const int kbase_ = (kt_) * 64;                                           \
        _Pragma("unroll")                                                        \
        for (int c = 0; c < 2; ++c) {                                            \
            const int row = c * 32 + wid * 8 + r8;                               \
            const int slot = s8 ^ (row & 7);                                     \
            GLL16(Kb + (size_t)(kbase_ + row) * 64 + slot * 8,                   \
                  (char*)&Ks[b_][0] + c * 4096 + wid * 1024);                    \
            GLL16(Vb + (size_t)row * 2048 + kbase_ + slot * 8,                   \
                  (char*)&Vs[b_][0] + c * 4096 + wid * 1024);                    \
        }                                                                        \
    } while (0)

    STAGE(0, 0);
    __syncthreads();
    int buf = 0;
    for (int kt = 0; kt <= lt; ++kt) {
        if (kt < lt) STAGE(buf ^ 1, kt + 1);
        const int kbase = kt * 64;
        const short* Kt = &Ks[buf][0];
        const short* Vt = &Vs[buf][0];
        // K fragments (shared by both strips): row=16kb+ql, slots g / 4+g
        bf16x8 kf[4][2];
        #pragma unroll
        for (int kb = 0; kb < 4; ++kb) {
            const int row = 16 * kb + ql;
            const int x = row & 7;
            kf[kb][0] = *(const bf16x8*)((const char*)Kt + row * 128 + ((g ^ x) << 4));
            kf[kb][1] = *(const bf16x8*)((const char*)Kt + row * 128 + (((4 + g) ^ x) << 4));
        }
        #pragma unroll
        for (int qs = 0; qs < 2; ++qs) {
            const int q0s = q0w + 16 * qs;
            if (kbase > q0s + 15) continue;   // fully above diagonal: all masked
            // S^T[k][q]: s[kb][r] = S[kbase+16kb+4g+r][q0s+ql]
            f32x4 s[4];
            #pragma unroll
            for (int kb = 0; kb < 4; ++kb) {
                f32x4 z = {0.f, 0.f, 0.f, 0.f};
                z = __builtin_amdgcn_mfma_f32_16x16x32_bf16(kf[kb][0], qf[qs][0], z, 0, 0, 0);
                z = __builtin_amdgcn_mfma_f32_16x16x32_bf16(kf[kb][1], qf[qs][1], z, 0, 0, 0);
                s[kb] = z;
            }
            if (kbase + 63 > q0s) {           // tile touches/crosses diagonal: mask
                #pragma unroll
                for (int kb = 0; kb < 4; ++kb)
                    #pragma unroll
                    for (int r = 0; r < 4; ++r)
                        if (kbase + 16 * kb + 4 * g + r > q0s + ql) s[kb][r] = -1e30f;
            }
            // row max over k for q=ql: register tree + 2 shfl
            float t0 = fmaxf(fmaxf(s[0][0], s[0][1]), fmaxf(s[0][2], s[0][3]));
            float t1 = fmaxf(fmaxf(s[1][0], s[1][1]), fmaxf(s[1][2], s[1][3]));
            float t2 = fmaxf(fmaxf(s[2][0], s[2][1]), fmaxf(s[2][2], s[2][3]));
            float t3 = fmaxf(fmaxf(s[3][0], s[3][1]), fmaxf(s[3][2], s[3][3]));
            float tmax = fmaxf(fmaxf(t0, t1), fmaxf(t2, t3));
            tmax = fmaxf(tmax, __shfl_xor(tmax, 16));
            tmax = fmaxf(tmax, __shfl_xor(tmax, 32));
            const float mnew = fmaxf(m[qs], tmax);
            const float sc = __expf(m[qs] - mnew);
            m[qs] = mnew;
            float rsum = 0.0f;
            #pragma unroll
            for (int kb = 0; kb < 4; ++kb) {
                const float e0 = __expf(s[kb][0] - mnew);
                const float e1 = __expf(s[kb][1] - mnew);
                const float e2 = __expf(s[kb][2] - mnew);
                const float e3 = __expf(s[kb][3] - mnew);
                rsum += (e0 + e1) + (e2 + e3);
                short4 pk;
                pk.x = f2bf(e0); pk.y = f2bf(e1); pk.z = f2bf(e2); pk.w = f2bf(e3);
                *(short4*)&Pw[ql * 72 + 16 * kb + 4 * g] = pk;
            }
            rsum += __shfl_xor(rsum, 16);
            rsum += __shfl_xor(rsum, 32);
            lsum[qs] = lsum[qs] * sc + rsum;
            #pragma unroll
            for (int nf = 0; nf < 4; ++nf)
                #pragma unroll
                for (int r = 0; r < 4; ++r) o[qs][nf][r] *= sc;
            // O^T += V^T * P ; V^T frags from swizzled LDS, P from per-wave LDS
            const bf16x8 pb0 = *(const bf16x8*)&Pw[ql * 72 + 8 * g];
            const bf16x8 pb1 = *(const bf16x8*)&Pw[ql * 72 + 32 + 8 * g];
            #pragma unroll
            for (int nf = 0; nf < 4; ++nf) {
                const int row = 16 * nf + ql;
                const int x = row & 7;
                bf16x8 v0 = *(const bf16x8*)((const char*)Vt + row * 128 + ((g ^ x) << 4));
                bf16x8 v1 = *(const bf16x8*)((const char*)Vt + row * 128 + (((4 + g) ^ x) << 4));
                o[qs][nf] = __builtin_amdgcn_mfma_f32_16x16x32_bf16(v0, pb0, o[qs][nf], 0, 0, 0);
                o[qs][nf] = __builtin_amdgcn_mfma_f32_16x16x32_bf16(v1, pb1, o[qs][nf], 0, 0, 0);
            }
        }
        __syncthreads();
        buf ^= 1;
    }
#undef STAGE
    // write output: lane (ql,g) holds q=q0s+ql, d=16nf+4g+r
    const int b = bh >> 4, h = bh & 15;
    #pragma unroll
    for (int qs = 0; qs < 2; ++qs) {
        const float inv = 1.0f / lsum[qs];
        const size_t rowoff = ((size_t)b * 2048 + q0w + 16 * qs + ql) * 1024 + h * 64;
        #pragma unroll
        for (int nf = 0; nf < 4; ++nf) {
            short4 w;
            w.x = f2bf(o[qs][nf][0] * inv);
            w.y = f2bf(o[qs][nf][1] * inv);
            w.z = f2bf(o[qs][nf][2] * inv);
            w.w = f2bf(o[qs][nf][3] * inv);
            *(short4*)&Y[rowoff + 16 * nf + 4 * g] = w;
        }
    }
}

// ---------------- Hyperbolic residual: out = expmap(x, v, c), per-head wave ------
__global__ __launch_bounds__(256) void expmap_kernel(const float* __restrict__ x,
                                                     const float* __restrict__ v,
                                                     const float* __restrict__ carr,
                                                     float* __restrict__ out) {
    const int blk = blockIdx.x;
    const int row = blk >> 2;
    const int head = (blk & 3) * 4 + (threadIdx.x >> 6);
    const int lane = threadIdx.x & 63;
    const size_t idx = (size_t)row * 1024 + head * 64 + lane;
    float c = carr[head];
    c = fminf(fmaxf(c, 1e-4f), 1.0f);
    const float xe = x[idx], ve = v[idx];
    const float xn = wred(xe * xe);
    const float vns = wred(ve * ve);
    const float vn = sqrtf(vns + 1e-9f);
    const float sf = 2.0f / (1.0f + c * xn + 1e-9f);
    const float targ = fabsf(0.5f * c * sf * vns);
    const float coeff = (1.0f / (sqrtf(c + 1e-9f) + 1e-9f)) * tanhf(sqrtf(targ + 1e-9f));
    const float ye = coeff * ve / (vn + 1e-9f);
    const float yn = wred(ye * ye);
    const float ip = wred(xe * ye);
    const float num = (1.0f + 2.0f * c * ip + c * yn) * xe + (1.0f - c * xn) * ye;
    const float den = 1.0f + 2.0f * c * ip + c * c * xn * yn;
    out[idx] = num / (den + 1e-9f);
}

extern "C" void kernel_launch(void* const* d_in, const int* in_sizes, int n_in,
                              void* d_out, int out_size, void* d_ws, size_t ws_size,
                              hipStream_t stream) {
    (void)in_sizes; (void)n_in; (void)out_size; (void)ws_size;
    const float* x      = (const float*)d_in[0];
    const float* ln1_g  = (const float*)d_in[1];
    const float* w_qkv  = (const float*)d_in[2];
    const float* w_proj = (const float*)d_in[3];
    const float* c_attn = (const float*)d_in[4];
    const float* ln2_g  = (const float*)d_in[5];
    const float* w_fc   = (const float*)d_in[6];
    const float* w_mlp  = (const float*)d_in[7];
    const float* c_mlp  = (const float*)d_in[8];
    float* out = (float*)d_out;
    char* ws = (char*)d_ws;
    const size_t MB = 1024 * 1024;

    short* wqkv_bf  = (short*)(ws + 0 * MB);    // 6 MB
    short* wproj_bf = (short*)(ws + 6 * MB);    // 2 MB
    short* wfc_bf   = (short*)(ws + 8 * MB);    // 8 MB
    short* wmlp_bf  = (short*)(ws + 16 * MB);   // 8 MB
    short* y_bf     = (short*)(ws + 24 * MB);   // 8 MB (LN1 out; reused for LN2 out)
    short* q_bf     = (short*)(ws + 32 * MB);   // 8 MB
    short* k_bf     = (short*)(ws + 40 * MB);   // 8 MB
    short* vT_bf    = (short*)(ws + 48 * MB);   // 8 MB
    short* att_bf   = (short*)(ws + 56 * MB);   // 8 MB
    float* a_f32    = (float*)(ws + 64 * MB);   // 16 MB
    float* x1       = (float*)(ws + 80 * MB);   // 16 MB
    short* g_bf     = (short*)(ws + 32 * MB);   // 32 MB (reuses q/k/vT/att)
    float* h_f32    = (float*)(ws + 64 * MB);   // 16 MB (reuses a)

    cvt_kernel<<<3072, 256, 0, stream>>>(w_qkv, wqkv_bf, 3072 * 1024 / 4);
    cvt_kernel<<<1024, 256, 0, stream>>>(w_proj, wproj_bf, 1024 * 1024 / 4);
    cvt_kernel<<<4096, 256, 0, stream>>>(w_fc, wfc_bf, 4096 * 1024 / 4);
    cvt_kernel<<<4096, 256, 0, stream>>>(w_mlp, wmlp_bf, 1024 * 4096 / 4);

    ln_kernel<<<4096, 256, 0, stream>>>(x, ln1_g, y_bf);
    gemm_bt<0><<<dim3(32, 24), 256, 0, stream>>>(y_bf, wqkv_bf, 4096, 3072, 1024,
                                                 q_bf, k_bf, vT_bf);
    attn_kernel<<<dim3(16, 32), 256, 0, stream>>>(q_bf, k_bf, vT_bf, att_bf);
    gemm_bt<1><<<dim3(32, 8), 256, 0, stream>>>(att_bf, wproj_bf, 4096, 1024, 1024,
                                                a_f32, nullptr, nullptr);
    expmap_kernel<<<16384, 256, 0, stream>>>(x, a_f32, c_attn, x1);
    ln_kernel<<<4096, 256, 0, stream>>>(x1, ln2_g, y_bf);
    gemm_bt<2><<<dim3(32, 32), 256, 0, stream>>>(y_bf, wfc_bf, 4096, 4096, 1024,
                                                 g_bf, nullptr, nullptr);
    gemm_bt<1><<<dim3(32, 8), 256, 0, stream>>>(g_bf, wmlp_bf, 4096, 1024, 4096,
                                                h_f32, nullptr, nullptr);
    expmap_kernel<<<16384, 256, 0, stream>>>(x1, h_f32, c_mlp, out);
}

// Round 8
// 311.018 us; speedup vs baseline: 1.4303x; 1.0733x over previous
//
#include <hip/hip_runtime.h>
#include <hip/hip_bf16.h>

typedef __attribute__((ext_vector_type(8))) short bf16x8;
typedef __attribute__((ext_vector_type(4))) float f32x4;

typedef const __attribute__((address_space(1))) void gv_t;
typedef __attribute__((address_space(3))) void lv_t;
#define GLL16(g, l) __builtin_amdgcn_global_load_lds((gv_t*)(g), (lv_t*)(l), 16, 0, 0)

__device__ __forceinline__ short f2bf(float f) {
    __hip_bfloat16 h = __float2bfloat16(f);
    return *reinterpret_cast<short*>(&h);
}

__device__ __forceinline__ float wred(float v) {
    #pragma unroll
    for (int m = 1; m < 64; m <<= 1) v += __shfl_xor(v, m);
    return v;
}

// ---------------- fp32 -> bf16 convert (weights) ----------------
__global__ __launch_bounds__(256) void cvt_kernel(const float* __restrict__ in,
                                                  short* __restrict__ out, int n4) {
    int i = blockIdx.x * 256 + threadIdx.x;
    if (i < n4) {
        float4 v = ((const float4*)in)[i];
        short4 o;
        o.x = f2bf(v.x); o.y = f2bf(v.y); o.z = f2bf(v.z); o.w = f2bf(v.w);
        ((short4*)out)[i] = o;
    }
}

// ---------------- LayerNorm (fp32 in, bf16 out), row = 1024 ----------------
__global__ __launch_bounds__(256) void ln_kernel(const float* __restrict__ x,
                                                 const float* __restrict__ g,
                                                 short* __restrict__ y) {
    const int row = blockIdx.x, tid = threadIdx.x;
    const float4 v = ((const float4*)(x + (size_t)row * 1024))[tid];
    float s = v.x + v.y + v.z + v.w;
    float s2 = v.x * v.x + v.y * v.y + v.z * v.z + v.w * v.w;
    #pragma unroll
    for (int m = 1; m < 64; m <<= 1) { s += __shfl_xor(s, m); s2 += __shfl_xor(s2, m); }
    __shared__ float rs[4], rs2[4];
    if ((tid & 63) == 0) { rs[tid >> 6] = s; rs2[tid >> 6] = s2; }
    __syncthreads();
    s = rs[0] + rs[1] + rs[2] + rs[3];
    s2 = rs2[0] + rs2[1] + rs2[2] + rs2[3];
    const float mean = s * (1.0f / 1024.0f);
    const float var = s2 * (1.0f / 1024.0f) - mean * mean;
    const float r = rsqrtf(var + 1e-5f);
    const float4 gg = ((const float4*)g)[tid];
    short4 o;
    o.x = f2bf((v.x - mean) * r * gg.x);
    o.y = f2bf((v.y - mean) * r * gg.y);
    o.z = f2bf((v.z - mean) * r * gg.z);
    o.w = f2bf((v.w - mean) * r * gg.w);
    ((short4*)y)[(size_t)row * 256 + tid] = o;
}

// ---------------- GEMM: C[M,N] = A[M,K] * B[N,K]^T, bf16 in, templated epilogue ----
// BK=64, double-buffered LDS (64 KB), 1 barrier per K-step; staging of step t+1
// issued before compute of step t.  8-slot XOR swizzle (slot ^= row&7) on the
// global_load_lds SOURCE, inverted on the ds_read side -> bank-optimal b128 reads.
// EPI 0: QKV split -> q[b,h,t,d] (pre-scaled by 1/8), k[b,h,t,d], vT[b,h,d,t] (bf16)
// EPI 1: fp32 row-major
// EPI 2: exact GELU -> bf16 row-major
template <int EPI>
__global__ __launch_bounds__(256, 2) void gemm_bt(const short* __restrict__ A,
                                                  const short* __restrict__ Bw,
                                                  int M, int N, int K,
                                                  void* __restrict__ o0,
                                                  void* __restrict__ o1,
                                                  void* __restrict__ o2) {
    __shared__ __align__(16) short As[2][128 * 64];   // 32 KB
    __shared__ __align__(16) short Bs[2][128 * 64];   // 32 KB
    const int tid = threadIdx.x;
    const int wid = tid >> 6, lane = tid & 63;
    const int wm = wid >> 1, wn = wid & 1;
    const int col = lane & 15, grp = lane >> 4;
    const int r8 = lane >> 3, s8 = lane & 7;
    const int m0 = blockIdx.x * 128, n0 = blockIdx.y * 128;
    f32x4 acc[4][4] = {};
    const short* ga = A + (size_t)m0 * K;
    const short* gb = Bw + (size_t)n0 * K;

    // stage K-step t into buffer b_: 128 rows x 64 shorts per operand
#define GSTAGE(b_, t_) do {                                                     \
        const int k0_ = (t_) * 64;                                              \
        _Pragma("unroll")                                                       \
        for (int c = 0; c < 4; ++c) {                                           \
            const int row = c * 32 + wid * 8 + r8;                              \
            const int slot = s8 ^ (row & 7);                                    \
            GLL16(ga + (size_t)row * K + k0_ + slot * 8,                        \
                  (char*)&As[b_][0] + c * 4096 + wid * 1024);                   \
            GLL16(gb + (size_t)row * K + k0_ + slot * 8,                        \
                  (char*)&Bs[b_][0] + c * 4096 + wid * 1024);                   \
        }                                                                       \
    } while (0)

    const int NT = K >> 6;
    GSTAGE(0, 0);
    __syncthreads();
    int buf = 0;
    for (int t = 0; t < NT; ++t) {
        if (t + 1 < NT) GSTAGE(buf ^ 1, t + 1);
        const char* At = (const char*)&As[buf][0];
        const char* Bt = (const char*)&Bs[buf][0];
        #pragma unroll
        for (int s = 0; s < 2; ++s) {
            bf16x8 af[4], bfr[4];
            #pragma unroll
            for (int i = 0; i < 4; ++i) {
                const int rowA = wm * 64 + i * 16 + col;
                const int rowB = wn * 64 + i * 16 + col;
                af[i]  = *(const bf16x8*)(At + rowA * 128 + (((s * 4 + grp) ^ (rowA & 7)) << 4));
                bfr[i] = *(const bf16x8*)(Bt + rowB * 128 + (((s * 4 + grp) ^ (rowB & 7)) << 4));
            }
            #pragma unroll
            for (int mi = 0; mi < 4; ++mi)
                #pragma unroll
                for (int ni = 0; ni < 4; ++ni)
                    acc[mi][ni] = __builtin_amdgcn_mfma_f32_16x16x32_bf16(af[mi], bfr[ni], acc[mi][ni], 0, 0, 0);
        }
        __syncthreads();
        buf ^= 1;
    }
#undef GSTAGE
    #pragma unroll
    for (int mi = 0; mi < 4; ++mi) {
        #pragma unroll
        for (int ni = 0; ni < 4; ++ni) {
            #pragma unroll
            for (int i = 0; i < 4; ++i) {
                const int m = m0 + wm * 64 + mi * 16 + grp * 4 + i;
                const int n = n0 + wn * 64 + ni * 16 + col;
                const float v = acc[mi][ni][i];
                if (EPI == 0) {
                    const int b = m >> 11, t = m & 2047;
                    const int which = n >> 10, nn = n & 1023;
                    const int h = nn >> 6, d = nn & 63;
                    const size_t bh = (size_t)(b * 16 + h);
                    if (which == 0)
                        ((short*)o0)[(bh * 2048 + t) * 64 + d] = f2bf(v * 0.125f);
                    else if (which == 1)
                        ((short*)o1)[(bh * 2048 + t) * 64 + d] = f2bf(v);
                    else
                        ((short*)o2)[(bh * 64 + d) * 2048 + t] = f2bf(v);
                } else if (EPI == 1) {
                    ((float*)o0)[(size_t)m * N + n] = v;
                } else {
                    const float gl = 0.5f * v * (1.0f + erff(v * 0.70710678118654752f));
                    ((short*)o0)[(size_t)m * N + n] = f2bf(gl);
                }
            }
        }
    }
}

// ---------------- Flash attention, causal, LDS-staged K/V, 128-row q-tile ---------
// (unchanged from round 7 — verified)
__global__ __launch_bounds__(256, 3) void attn_kernel(const short* __restrict__ Q,
                                                      const short* __restrict__ Kg,
                                                      const short* __restrict__ VT,
                                                      short* __restrict__ Y) {
    __shared__ __align__(16) short Ks[2][4096];
    __shared__ __align__(16) short Vs[2][4096];
    __shared__ __align__(16) short Plds[4][16 * 72];
    const int j = 15 - blockIdx.x;
    const int bh = blockIdx.y;
    const int tid = threadIdx.x, wid = tid >> 6, lane = tid & 63;
    const int ql = lane & 15, g = lane >> 4;
    const int r8 = lane >> 3, s8 = lane & 7;
    const int q0w = j * 128 + wid * 32;
    const int lt = 2 * j + 1;
    const short* Qb = Q + (size_t)bh * 2048 * 64;
    const short* Kb = Kg + (size_t)bh * 2048 * 64;
    const short* Vb = VT + (size_t)bh * 64 * 2048;
    short* Pw = &Plds[wid][0];

    bf16x8 qf[2][2];
    #pragma unroll
    for (int qs = 0; qs < 2; ++qs) {
        qf[qs][0] = *(const bf16x8*)&Qb[(size_t)(q0w + 16 * qs + ql) * 64 + 8 * g];
        qf[qs][1] = *(const bf16x8*)&Qb[(size_t)(q0w + 16 * qs + ql) * 64 + 32 + 8 * g];
    }
    f32x4 o[2][4] = {};
    float m[2] = {-1e30f, -1e30f}, lsum[2] = {0.f, 0.f};

#define STAGE(b_, kt_) do {                                                      \
        const int kbase_ = (kt_) * 64;                                           \
        _Pragma("unroll")                                                        \
        for (int c = 0; c < 2; ++c) {                                            \
            const int row = c * 32 + wid * 8 + r8;                               \
            const int slot = s8 ^ (row & 7);                                     \
            GLL16(Kb + (size_t)(kbase_ + row) * 64 + slot * 8,                   \
                  (char*)&Ks[b_][0] + c * 4096 + wid * 1024);                    \
            GLL16(Vb + (size_t)row * 2048 + kbase_ + slot * 8,                   \
                  (char*)&Vs[b_][0] + c * 4096 + wid * 1024);                    \
        }                                                                        \
    } while (0)

    STAGE(0, 0);
    __syncthreads();
    int buf = 0;
    for (int kt = 0; kt <= lt; ++kt) {
        if (kt < lt) STAGE(buf ^ 1, kt + 1);
        const int kbase = kt * 64;
        const short* Kt = &Ks[buf][0];
        const short* Vt = &Vs[buf][0];
        bf16x8 kf[4][2];
        #pragma unroll
        for (int kb = 0; kb < 4; ++kb) {
            const int row = 16 * kb + ql;
            const int x = row & 7;
            kf[kb][0] = *(const bf16x8*)((const char*)Kt + row * 128 + ((g ^ x) << 4));
            kf[kb][1] = *(const bf16x8*)((const char*)Kt + row * 128 + (((4 + g) ^ x) << 4));
        }
        #pragma unroll
        for (int qs = 0; qs < 2; ++qs) {
            const int q0s = q0w + 16 * qs;
            if (kbase > q0s + 15) continue;
            f32x4 s[4];
            #pragma unroll
            for (int kb = 0; kb < 4; ++kb) {
                f32x4 z = {0.f, 0.f, 0.f, 0.f};
                z = __builtin_amdgcn_mfma_f32_16x16x32_bf16(kf[kb][0], qf[qs][0], z, 0, 0, 0);
                z = __builtin_amdgcn_mfma_f32_16x16x32_bf16(kf[kb][1], qf[qs][1], z, 0, 0, 0);
                s[kb] = z;
            }
            if (kbase + 63 > q0s) {
                #pragma unroll
                for (int kb = 0; kb < 4; ++kb)
                    #pragma unroll
                    for (int r = 0; r < 4; ++r)
                        if (kbase + 16 * kb + 4 * g + r > q0s + ql) s[kb][r] = -1e30f;
            }
            float t0 = fmaxf(fmaxf(s[0][0], s[0][1]), fmaxf(s[0][2], s[0][3]));
            float t1 = fmaxf(fmaxf(s[1][0], s[1][1]), fmaxf(s[1][2], s[1][3]));
            float t2 = fmaxf(fmaxf(s[2][0], s[2][1]), fmaxf(s[2][2], s[2][3]));
            float t3 = fmaxf(fmaxf(s[3][0], s[3][1]), fmaxf(s[3][2], s[3][3]));
            float tmax = fmaxf(fmaxf(t0, t1), fmaxf(t2, t3));
            tmax = fmaxf(tmax, __shfl_xor(tmax, 16));
            tmax = fmaxf(tmax, __shfl_xor(tmax, 32));
            const float mnew = fmaxf(m[qs], tmax);
            const float sc = __expf(m[qs] - mnew);
            m[qs] = mnew;
            float rsum = 0.0f;
            #pragma unroll
            for (int kb = 0; kb < 4; ++kb) {
                const float e0 = __expf(s[kb][0] - mnew);
                const float e1 = __expf(s[kb][1] - mnew);
                const float e2 = __expf(s[kb][2] - mnew);
                const float e3 = __expf(s[kb][3] - mnew);
                rsum += (e0 + e1) + (e2 + e3);
                short4 pk;
                pk.x = f2bf(e0); pk.y = f2bf(e1); pk.z = f2bf(e2); pk.w = f2bf(e3);
                *(short4*)&Pw[ql * 72 + 16 * kb + 4 * g] = pk;
            }
            rsum += __shfl_xor(rsum, 16);
            rsum += __shfl_xor(rsum, 32);
            lsum[qs] = lsum[qs] * sc + rsum;
            #pragma unroll
            for (int nf = 0; nf < 4; ++nf)
                #pragma unroll
                for (int r = 0; r < 4; ++r) o[qs][nf][r] *= sc;
            const bf16x8 pb0 = *(const bf16x8*)&Pw[ql * 72 + 8 * g];
            const bf16x8 pb1 = *(const bf16x8*)&Pw[ql * 72 + 32 + 8 * g];
            #pragma unroll
            for (int nf = 0; nf < 4; ++nf) {
                const int row = 16 * nf + ql;
                const int x = row & 7;
                bf16x8 v0 = *(const bf16x8*)((const char*)Vt + row * 128 + ((g ^ x) << 4));
                bf16x8 v1 = *(const bf16x8*)((const char*)Vt + row * 128 + (((4 + g) ^ x) << 4));
                o[qs][nf] = __builtin_amdgcn_mfma_f32_16x16x32_bf16(v0, pb0, o[qs][nf], 0, 0, 0);
                o[qs][nf] = __builtin_amdgcn_mfma_f32_16x16x32_bf16(v1, pb1, o[qs][nf], 0, 0, 0);
            }
        }
        __syncthreads();
        buf ^= 1;
    }
#undef STAGE
    const int b = bh >> 4, h = bh & 15;
    #pragma unroll
    for (int qs = 0; qs < 2; ++qs) {
        const float inv = 1.0f / lsum[qs];
        const size_t rowoff = ((size_t)b * 2048 + q0w + 16 * qs + ql) * 1024 + h * 64;
        #pragma unroll
        for (int nf = 0; nf < 4; ++nf) {
            short4 w;
            w.x = f2bf(o[qs][nf][0] * inv);
            w.y = f2bf(o[qs][nf][1] * inv);
            w.z = f2bf(o[qs][nf][2] * inv);
            w.w = f2bf(o[qs][nf][3] * inv);
            *(short4*)&Y[rowoff + 16 * nf + 4 * g] = w;
        }
    }
}

// ---------------- Hyperbolic residual: out = expmap(x, v, c), per-head wave ------
__global__ __launch_bounds__(256) void expmap_kernel(const float* __restrict__ x,
                                                     const float* __restrict__ v,
                                                     const float* __restrict__ carr,
                                                     float* __restrict__ out) {
    const int blk = blockIdx.x;
    const int row = blk >> 2;
    const int head = (blk & 3) * 4 + (threadIdx.x >> 6);
    const int lane = threadIdx.x & 63;
    const size_t idx = (size_t)row * 1024 + head * 64 + lane;
    float c = carr[head];
    c = fminf(fmaxf(c, 1e-4f), 1.0f);
    const float xe = x[idx], ve = v[idx];
    const float xn = wred(xe * xe);
    const float vns = wred(ve * ve);
    const float vn = sqrtf(vns + 1e-9f);
    const float sf = 2.0f / (1.0f + c * xn + 1e-9f);
    const float targ = fabsf(0.5f * c * sf * vns);
    const float coeff = (1.0f / (sqrtf(c + 1e-9f) + 1e-9f)) * tanhf(sqrtf(targ + 1e-9f));
    const float ye = coeff * ve / (vn + 1e-9f);
    const float yn = wred(ye * ye);
    const float ip = wred(xe * ye);
    const float num = (1.0f + 2.0f * c * ip + c * yn) * xe + (1.0f - c * xn) * ye;
    const float den = 1.0f + 2.0f * c * ip + c * c * xn * yn;
    out[idx] = num / (den + 1e-9f);
}

extern "C" void kernel_launch(void* const* d_in, const int* in_sizes, int n_in,
                              void* d_out, int out_size, void* d_ws, size_t ws_size,
                              hipStream_t stream) {
    (void)in_sizes; (void)n_in; (void)out_size; (void)ws_size;
    const float* x      = (const float*)d_in[0];
    const float* ln1_g  = (const float*)d_in[1];
    const float* w_qkv  = (const float*)d_in[2];
    const float* w_proj = (const float*)d_in[3];
    const float* c_attn = (const float*)d_in[4];
    const float* ln2_g  = (const float*)d_in[5];
    const float* w_fc   = (const float*)d_in[6];
    const float* w_mlp  = (const float*)d_in[7];
    const float* c_mlp  = (const float*)d_in[8];
    float* out = (float*)d_out;
    char* ws = (char*)d_ws;
    const size_t MB = 1024 * 1024;

    short* wqkv_bf  = (short*)(ws + 0 * MB);    // 6 MB
    short* wproj_bf = (short*)(ws + 6 * MB);    // 2 MB
    short* wfc_bf   = (short*)(ws + 8 * MB);    // 8 MB
    short* wmlp_bf  = (short*)(ws + 16 * MB);   // 8 MB
    short* y_bf     = (short*)(ws + 24 * MB);   // 8 MB (LN1 out; reused for LN2 out)
    short* q_bf     = (short*)(ws + 32 * MB);   // 8 MB
    short* k_bf     = (short*)(ws + 40 * MB);   // 8 MB
    short* vT_bf    = (short*)(ws + 48 * MB);   // 8 MB
    short* att_bf   = (short*)(ws + 56 * MB);   // 8 MB
    float* a_f32    = (float*)(ws + 64 * MB);   // 16 MB
    float* x1       = (float*)(ws + 80 * MB);   // 16 MB
    short* g_bf     = (short*)(ws + 32 * MB);   // 32 MB (reuses q/k/vT/att)
    float* h_f32    = (float*)(ws + 64 * MB);   // 16 MB (reuses a)

    cvt_kernel<<<3072, 256, 0, stream>>>(w_qkv, wqkv_bf, 3072 * 1024 / 4);
    cvt_kernel<<<1024, 256, 0, stream>>>(w_proj, wproj_bf, 1024 * 1024 / 4);
    cvt_kernel<<<4096, 256, 0, stream>>>(w_fc, wfc_bf, 4096 * 1024 / 4);
    cvt_kernel<<<4096, 256, 0, stream>>>(w_mlp, wmlp_bf, 1024 * 4096 / 4);

    ln_kernel<<<4096, 256, 0, stream>>>(x, ln1_g, y_bf);
    gemm_bt<0><<<dim3(32, 24), 256, 0, stream>>>(y_bf, wqkv_bf, 4096, 3072, 1024,
                                                 q_bf, k_bf, vT_bf);
    attn_kernel<<<dim3(16, 32), 256, 0, stream>>>(q_bf, k_bf, vT_bf, att_bf);
    gemm_bt<1><<<dim3(32, 8), 256, 0, stream>>>(att_bf, wproj_bf, 4096, 1024, 1024,
                                                a_f32, nullptr, nullptr);
    expmap_kernel<<<16384, 256, 0, stream>>>(x, a_f32, c_attn, x1);
    ln_kernel<<<4096, 256, 0, stream>>>(x1, ln2_g, y_bf);
    gemm_bt<2><<<dim3(32, 32), 256, 0, stream>>>(y_bf, wfc_bf, 4096, 4096, 1024,
                                                 g_bf, nullptr, nullptr);
    gemm_bt<1><<<dim3(32, 8), 256, 0, stream>>>(g_bf, wmlp_bf, 4096, 1024, 4096,
                                                h_f32, nullptr, nullptr);
    expmap_kernel<<<16384, 256, 0, stream>>>(x1, h_f32, c_mlp, out);
}

// Round 9
// 303.122 us; speedup vs baseline: 1.4675x; 1.0260x over previous
//
#include <hip/hip_runtime.h>
#include <hip/hip_bf16.h>

typedef __attribute__((ext_vector_type(8))) short bf16x8;
typedef __attribute__((ext_vector_type(4))) float f32x4;

typedef const __attribute__((address_space(1))) void gv_t;
typedef __attribute__((address_space(3))) void lv_t;
#define GLL16(g, l) __builtin_amdgcn_global_load_lds((gv_t*)(g), (lv_t*)(l), 16, 0, 0)

#define WAITV8() asm volatile("s_waitcnt vmcnt(8)" ::: "memory")
#define WAITV0() asm volatile("s_waitcnt vmcnt(0)" ::: "memory")
#define WAITL0() asm volatile("s_waitcnt lgkmcnt(0)" ::: "memory")
#define SCHEDB() __builtin_amdgcn_sched_barrier(0)
#define BARRAW() __builtin_amdgcn_s_barrier()

__device__ __forceinline__ short f2bf(float f) {
    __hip_bfloat16 h = __float2bfloat16(f);
    return *reinterpret_cast<short*>(&h);
}

__device__ __forceinline__ float wred(float v) {
    #pragma unroll
    for (int m = 1; m < 64; m <<= 1) v += __shfl_xor(v, m);
    return v;
}

// ---------------- fp32 -> bf16 convert (weights) ----------------
__global__ __launch_bounds__(256) void cvt_kernel(const float* __restrict__ in,
                                                  short* __restrict__ out, int n4) {
    int i = blockIdx.x * 256 + threadIdx.x;
    if (i < n4) {
        float4 v = ((const float4*)in)[i];
        short4 o;
        o.x = f2bf(v.x); o.y = f2bf(v.y); o.z = f2bf(v.z); o.w = f2bf(v.w);
        ((short4*)out)[i] = o;
    }
}

// ---------------- LayerNorm (fp32 in, bf16 out), row = 1024 ----------------
__global__ __launch_bounds__(256) void ln_kernel(const float* __restrict__ x,
                                                 const float* __restrict__ g,
                                                 short* __restrict__ y) {
    const int row = blockIdx.x, tid = threadIdx.x;
    const float4 v = ((const float4*)(x + (size_t)row * 1024))[tid];
    float s = v.x + v.y + v.z + v.w;
    float s2 = v.x * v.x + v.y * v.y + v.z * v.z + v.w * v.w;
    #pragma unroll
    for (int m = 1; m < 64; m <<= 1) { s += __shfl_xor(s, m); s2 += __shfl_xor(s2, m); }
    __shared__ float rs[4], rs2[4];
    if ((tid & 63) == 0) { rs[tid >> 6] = s; rs2[tid >> 6] = s2; }
    __syncthreads();
    s = rs[0] + rs[1] + rs[2] + rs[3];
    s2 = rs2[0] + rs2[1] + rs2[2] + rs2[3];
    const float mean = s * (1.0f / 1024.0f);
    const float var = s2 * (1.0f / 1024.0f) - mean * mean;
    const float r = rsqrtf(var + 1e-5f);
    const float4 gg = ((const float4*)g)[tid];
    short4 o;
    o.x = f2bf((v.x - mean) * r * gg.x);
    o.y = f2bf((v.y - mean) * r * gg.y);
    o.z = f2bf((v.z - mean) * r * gg.z);
    o.w = f2bf((v.w - mean) * r * gg.w);
    ((short4*)y)[(size_t)row * 256 + tid] = o;
}

// ---------------- GEMM: C[M,N] = A[M,K] * B[N,K]^T, bf16 in, templated epilogue ----
// BK=64, double-buffered LDS (64 KB), counted-vmcnt pipeline: raw s_barrier with
// explicit s_waitcnt — prefetch loads stay in flight across barriers (never
// vmcnt(0) in steady state).  8-slot XOR swizzle on the global_load_lds SOURCE,
// inverted on the ds_read side (zero bank conflicts, verified round 8).
// EPI 0: QKV split -> q (pre-scaled 1/8), k, vT   EPI 1: fp32   EPI 2: GELU bf16
template <int EPI>
__global__ __launch_bounds__(256, 2) void gemm_bt(const short* __restrict__ A,
                                                  const short* __restrict__ Bw,
                                                  int M, int N, int K,
                                                  void* __restrict__ o0,
                                                  void* __restrict__ o1,
                                                  void* __restrict__ o2) {
    __shared__ __align__(16) short As[2][128 * 64];   // 32 KB
    __shared__ __align__(16) short Bs[2][128 * 64];   // 32 KB
    const int tid = threadIdx.x;
    const int wid = tid >> 6, lane = tid & 63;
    const int wm = wid >> 1, wn = wid & 1;
    const int col = lane & 15, grp = lane >> 4;
    const int r8 = lane >> 3, s8 = lane & 7;
    const int m0 = blockIdx.x * 128, n0 = blockIdx.y * 128;
    f32x4 acc[4][4] = {};
    const short* ga = A + (size_t)m0 * K;
    const short* gb = Bw + (size_t)n0 * K;

#define GSTAGE(b_, t_) do {                                                     \
        const int k0_ = (t_) * 64;                                              \
        _Pragma("unroll")                                                       \
        for (int c = 0; c < 4; ++c) {                                           \
            const int row = c * 32 + wid * 8 + r8;                              \
            const int slot = s8 ^ (row & 7);                                    \
            GLL16(ga + (size_t)row * K + k0_ + slot * 8,                        \
                  (char*)&As[b_][0] + c * 4096 + wid * 1024);                   \
            GLL16(gb + (size_t)row * K + k0_ + slot * 8,                        \
                  (char*)&Bs[b_][0] + c * 4096 + wid * 1024);                   \
        }                                                                       \
    } while (0)

    const int NT = K >> 6;
    GSTAGE(0, 0);
    if (NT > 1) { GSTAGE(1, 1); WAITV8(); } else { WAITV0(); }
    SCHEDB();
    BARRAW();
    int cur = 0;
    for (int t = 0; t < NT; ++t) {
        const char* At = (const char*)&As[cur][0];
        const char* Bt = (const char*)&Bs[cur][0];
        // (a) read ALL fragments for this K-step into registers
        bf16x8 af[2][4], bfr[2][4];
        #pragma unroll
        for (int s = 0; s < 2; ++s)
            #pragma unroll
            for (int i = 0; i < 4; ++i) {
                const int rowA = wm * 64 + i * 16 + col;
                const int rowB = wn * 64 + i * 16 + col;
                af[s][i]  = *(const bf16x8*)(At + rowA * 128 + (((s * 4 + grp) ^ (rowA & 7)) << 4));
                bfr[s][i] = *(const bf16x8*)(Bt + rowB * 128 + (((s * 4 + grp) ^ (rowB & 7)) << 4));
            }
        WAITL0(); SCHEDB();      // reads retired -> WAR-safe to overwrite after barrier
        BARRAW();
        // (c) refill the just-freed buffer with K-step t+2 (stays in flight)
        if (t + 2 < NT) GSTAGE(cur, t + 2);
        // (d) MFMA on registers
        #pragma unroll
        for (int s = 0; s < 2; ++s)
            #pragma unroll
            for (int mi = 0; mi < 4; ++mi)
                #pragma unroll
                for (int ni = 0; ni < 4; ++ni)
                    acc[mi][ni] = __builtin_amdgcn_mfma_f32_16x16x32_bf16(af[s][mi], bfr[s][ni], acc[mi][ni], 0, 0, 0);
        // (e) wait for NEXT tile's loads only (t+2's 8 remain outstanding)
        if (t + 1 < NT) {
            if (t + 2 < NT) { WAITV8(); } else { WAITV0(); }
            SCHEDB();
            BARRAW();
        }
        cur ^= 1;
    }
#undef GSTAGE
    #pragma unroll
    for (int mi = 0; mi < 4; ++mi) {
        #pragma unroll
        for (int ni = 0; ni < 4; ++ni) {
            #pragma unroll
            for (int i = 0; i < 4; ++i) {
                const int m = m0 + wm * 64 + mi * 16 + grp * 4 + i;
                const int n = n0 + wn * 64 + ni * 16 + col;
                const float v = acc[mi][ni][i];
                if (EPI == 0) {
                    const int b = m >> 11, t = m & 2047;
                    const int which = n >> 10, nn = n & 1023;
                    const int h = nn >> 6, d = nn & 63;
                    const size_t bh = (size_t)(b * 16 + h);
                    if (which == 0)
                        ((short*)o0)[(bh * 2048 + t) * 64 + d] = f2bf(v * 0.125f);
                    else if (which == 1)
                        ((short*)o1)[(bh * 2048 + t) * 64 + d] = f2bf(v);
                    else
                        ((short*)o2)[(bh * 64 + d) * 2048 + t] = f2bf(v);
                } else if (EPI == 1) {
                    ((float*)o0)[(size_t)m * N + n] = v;
                } else {
                    const float gl = 0.5f * v * (1.0f + erff(v * 0.70710678118654752f));
                    ((short*)o0)[(size_t)m * N + n] = f2bf(gl);
                }
            }
        }
    }
}

// ---------------- Flash attention, causal, LDS-staged K/V, 128-row q-tile ---------
// (unchanged — verified)
__global__ __launch_bounds__(256, 3) void attn_kernel(const short* __restrict__ Q,
                                                      const short* __restrict__ Kg,
                                                      const short* __restrict__ VT,
                                                      short* __restrict__ Y) {
    __shared__ __align__(16) short Ks[2][4096];
    __shared__ __align__(16) short Vs[2][4096];
    __shared__ __align__(16) short Plds[4][16 * 72];
    const int j = 15 - blockIdx.x;
    const int bh = blockIdx.y;
    const int tid = threadIdx.x, wid = tid >> 6, lane = tid & 63;
    const int ql = lane & 15, g = lane >> 4;
    const int r8 = lane >> 3, s8 = lane & 7;
    const int q0w = j * 128 + wid * 32;
    const int lt = 2 * j + 1;
    const short* Qb = Q + (size_t)bh * 2048 * 64;
    const short* Kb = Kg + (size_t)bh * 2048 * 64;
    const short* Vb = VT + (size_t)bh * 64 * 2048;
    short* Pw = &Plds[wid][0];

    bf16x8 qf[2][2];
    #pragma unroll
    for (int qs = 0; qs < 2; ++qs) {
        qf[qs][0] = *(const bf16x8*)&Qb[(size_t)(q0w + 16 * qs + ql) * 64 + 8 * g];
        qf[qs][1] = *(const bf16x8*)&Qb[(size_t)(q0w + 16 * qs + ql) * 64 + 32 + 8 * g];
    }
    f32x4 o[2][4] = {};
    float m[2] = {-1e30f, -1e30f}, lsum[2] = {0.f, 0.f};

#define STAGE(b_, kt_) do {                                                      \
        const int kbase_ = (kt_) * 64;                                           \
        _Pragma("unroll")                                                        \
        for (int c = 0; c < 2; ++c) {                                            \
            const int row = c * 32 + wid * 8 + r8;                               \
            const int slot = s8 ^ (row & 7);                                     \
            GLL16(Kb + (size_t)(kbase_ + row) * 64 + slot * 8,                   \
                  (char*)&Ks[b_][0] + c * 4096 + wid * 1024);                    \
            GLL16(Vb + (size_t)row * 2048 + kbase_ + slot * 8,                   \
                  (char*)&Vs[b_][0] + c * 4096 + wid * 1024);                    \
        }                                                                        \
    } while (0)

    STAGE(0, 0);
    __syncthreads();
    int buf = 0;
    for (int kt = 0; kt <= lt; ++kt) {
        if (kt < lt) STAGE(buf ^ 1, kt + 1);
        const int kbase = kt * 64;
        const short* Kt = &Ks[buf][0];
        const short* Vt = &Vs[buf][0];
        bf16x8 kf[4][2];
        #pragma unroll
        for (int kb = 0; kb < 4; ++kb) {
            const int row = 16 * kb + ql;
            const int x = row & 7;
            kf[kb][0] = *(const bf16x8*)((const char*)Kt + row * 128 + ((g ^ x) << 4));
            kf[kb][1] = *(const bf16x8*)((const char*)Kt + row * 128 + (((4 + g) ^ x) << 4));
        }
        #pragma unroll
        for (int qs = 0; qs < 2; ++qs) {
            const int q0s = q0w + 16 * qs;
            if (kbase > q0s + 15) continue;
            f32x4 s[4];
            #pragma unroll
            for (int kb = 0; kb < 4; ++kb) {
                f32x4 z = {0.f, 0.f, 0.f, 0.f};
                z = __builtin_amdgcn_mfma_f32_16x16x32_bf16(kf[kb][0], qf[qs][0], z, 0, 0, 0);
                z = __builtin_amdgcn_mfma_f32_16x16x32_bf16(kf[kb][1], qf[qs][1], z, 0, 0, 0);
                s[kb] = z;
            }
            if (kbase + 63 > q0s) {
                #pragma unroll
                for (int kb = 0; kb < 4; ++kb)
                    #pragma unroll
                    for (int r = 0; r < 4; ++r)
                        if (kbase + 16 * kb + 4 * g + r > q0s + ql) s[kb][r] = -1e30f;
            }
            float t0 = fmaxf(fmaxf(s[0][0], s[0][1]), fmaxf(s[0][2], s[0][3]));
            float t1 = fmaxf(fmaxf(s[1][0], s[1][1]), fmaxf(s[1][2], s[1][3]));
            float t2 = fmaxf(fmaxf(s[2][0], s[2][1]), fmaxf(s[2][2], s[2][3]));
            float t3 = fmaxf(fmaxf(s[3][0], s[3][1]), fmaxf(s[3][2], s[3][3]));
            float tmax = fmaxf(fmaxf(t0, t1), fmaxf(t2, t3));
            tmax = fmaxf(tmax, __shfl_xor(tmax, 16));
            tmax = fmaxf(tmax, __shfl_xor(tmax, 32));
            const float mnew = fmaxf(m[qs], tmax);
            const float sc = __expf(m[qs] - mnew);
            m[qs] = mnew;
            float rsum = 0.0f;
            #pragma unroll
            for (int kb = 0; kb < 4; ++kb) {
                const float e0 = __expf(s[kb][0] - mnew);
                const float e1 = __expf(s[kb][1] - mnew);
                const float e2 = __expf(s[kb][2] - mnew);
                const float e3 = __expf(s[kb][3] - mnew);
                rsum += (e0 + e1) + (e2 + e3);
                short4 pk;
                pk.x = f2bf(e0); pk.y = f2bf(e1); pk.z = f2bf(e2); pk.w = f2bf(e3);
                *(short4*)&Pw[ql * 72 + 16 * kb + 4 * g] = pk;
            }
            rsum += __shfl_xor(rsum, 16);
            rsum += __shfl_xor(rsum, 32);
            lsum[qs] = lsum[qs] * sc + rsum;
            #pragma unroll
            for (int nf = 0; nf < 4; ++nf)
                #pragma unroll
                for (int r = 0; r < 4; ++r) o[qs][nf][r] *= sc;
            const bf16x8 pb0 = *(const bf16x8*)&Pw[ql * 72 + 8 * g];
            const bf16x8 pb1 = *(const bf16x8*)&Pw[ql * 72 + 32 + 8 * g];
            #pragma unroll
            for (int nf = 0; nf < 4; ++nf) {
                const int row = 16 * nf + ql;
                const int x = row & 7;
                bf16x8 v0 = *(const bf16x8*)((const char*)Vt + row * 128 + ((g ^ x) << 4));
                bf16x8 v1 = *(const bf16x8*)((const char*)Vt + row * 128 + (((4 + g) ^ x) << 4));
                o[qs][nf] = __builtin_amdgcn_mfma_f32_16x16x32_bf16(v0, pb0, o[qs][nf], 0, 0, 0);
                o[qs][nf] = __builtin_amdgcn_mfma_f32_16x16x32_bf16(v1, pb1, o[qs][nf], 0, 0, 0);
            }
        }
        __syncthreads();
        buf ^= 1;
    }
#undef STAGE
    const int b = bh >> 4, h = bh & 15;
    #pragma unroll
    for (int qs = 0; qs < 2; ++qs) {
        const float inv = 1.0f / lsum[qs];
        const size_t rowoff = ((size_t)b * 2048 + q0w + 16 * qs + ql) * 1024 + h * 64;
        #pragma unroll
        for (int nf = 0; nf < 4; ++nf) {
            short4 w;
            w.x = f2bf(o[qs][nf][0] * inv);
            w.y = f2bf(o[qs][nf][1] * inv);
            w.z = f2bf(o[qs][nf][2] * inv);
            w.w = f2bf(o[qs][nf][3] * inv);
            *(short4*)&Y[rowoff + 16 * nf + 4 * g] = w;
        }
    }
}

// ---------------- Hyperbolic residual: out = expmap(x, v, c), per-head wave ------
__global__ __launch_bounds__(256) void expmap_kernel(const float* __restrict__ x,
                                                     const float* __restrict__ v,
                                                     const float* __restrict__ carr,
                                                     float* __restrict__ out) {
    const int blk = blockIdx.x;
    const int row = blk >> 2;
    const int head = (blk & 3) * 4 + (threadIdx.x >> 6);
    const int lane = threadIdx.x & 63;
    const size_t idx = (size_t)row * 1024 + head * 64 + lane;
    float c = carr[head];
    c = fminf(fmaxf(c, 1e-4f), 1.0f);
    const float xe = x[idx], ve = v[idx];
    const float xn = wred(xe * xe);
    const float vns = wred(ve * ve);
    const float vn = sqrtf(vns + 1e-9f);
    const float sf = 2.0f / (1.0f + c * xn + 1e-9f);
    const float targ = fabsf(0.5f * c * sf * vns);
    const float coeff = (1.0f / (sqrtf(c + 1e-9f) + 1e-9f)) * tanhf(sqrtf(targ + 1e-9f));
    const float ye = coeff * ve / (vn + 1e-9f);
    const float yn = wred(ye * ye);
    const float ip = wred(xe * ye);
    const float num = (1.0f + 2.0f * c * ip + c * yn) * xe + (1.0f - c * xn) * ye;
    const float den = 1.0f + 2.0f * c * ip + c * c * xn * yn;
    out[idx] = num / (den + 1e-9f);
}

extern "C" void kernel_launch(void* const* d_in, const int* in_sizes, int n_in,
                              void* d_out, int out_size, void* d_ws, size_t ws_size,
                              hipStream_t stream) {
    (void)in_sizes; (void)n_in; (void)out_size; (void)ws_size;
    const float* x      = (const float*)d_in[0];
    const float* ln1_g  = (const float*)d_in[1];
    const float* w_qkv  = (const float*)d_in[2];
    const float* w_proj = (const float*)d_in[3];
    const float* c_attn = (const float*)d_in[4];
    const float* ln2_g  = (const float*)d_in[5];
    const float* w_fc   = (const float*)d_in[6];
    const float* w_mlp  = (const float*)d_in[7];
    const float* c_mlp  = (const float*)d_in[8];
    float* out = (float*)d_out;
    char* ws = (char*)d_ws;
    const size_t MB = 1024 * 1024;

    short* wqkv_bf  = (short*)(ws + 0 * MB);    // 6 MB
    short* wproj_bf = (short*)(ws + 6 * MB);    // 2 MB
    short* wfc_bf   = (short*)(ws + 8 * MB);    // 8 MB
    short* wmlp_bf  = (short*)(ws + 16 * MB);   // 8 MB
    short* y_bf     = (short*)(ws + 24 * MB);   // 8 MB (LN1 out; reused for LN2 out)
    short* q_bf     = (short*)(ws + 32 * MB);   // 8 MB
    short* k_bf     = (short*)(ws + 40 * MB);   // 8 MB
    short* vT_bf    = (short*)(ws + 48 * MB);   // 8 MB
    short* att_bf   = (short*)(ws + 56 * MB);   // 8 MB
    float* a_f32    = (float*)(ws + 64 * MB);   // 16 MB
    float* x1       = (float*)(ws + 80 * MB);   // 16 MB
    short* g_bf     = (short*)(ws + 32 * MB);   // 32 MB (reuses q/k/vT/att)
    float* h_f32    = (float*)(ws + 64 * MB);   // 16 MB (reuses a)

    cvt_kernel<<<3072, 256, 0, stream>>>(w_qkv, wqkv_bf, 3072 * 1024 / 4);
    cvt_kernel<<<1024, 256, 0, stream>>>(w_proj, wproj_bf, 1024 * 1024 / 4);
    cvt_kernel<<<4096, 256, 0, stream>>>(w_fc, wfc_bf, 4096 * 1024 / 4);
    cvt_kernel<<<4096, 256, 0, stream>>>(w_mlp, wmlp_bf, 1024 * 4096 / 4);

    ln_kernel<<<4096, 256, 0, stream>>>(x, ln1_g, y_bf);
    gemm_bt<0><<<dim3(32, 24), 256, 0, stream>>>(y_bf, wqkv_bf, 4096, 3072, 1024,
                                                 q_bf, k_bf, vT_bf);
    attn_kernel<<<dim3(16, 32), 256, 0, stream>>>(q_bf, k_bf, vT_bf, att_bf);
    gemm_bt<1><<<dim3(32, 8), 256, 0, stream>>>(att_bf, wproj_bf, 4096, 1024, 1024,
                                                a_f32, nullptr, nullptr);
    expmap_kernel<<<16384, 256, 0, stream>>>(x, a_f32, c_attn, x1);
    ln_kernel<<<4096, 256, 0, stream>>>(x1, ln2_g, y_bf);
    gemm_bt<2><<<dim3(32, 32), 256, 0, stream>>>(y_bf, wfc_bf, 4096, 4096, 1024,
                                                 g_bf, nullptr, nullptr);
    gemm_bt<1><<<dim3(32, 8), 256, 0, stream>>>(g_bf, wmlp_bf, 4096, 1024, 4096,
                                                h_f32, nullptr, nullptr);
    expmap_kernel<<<16384, 256, 0, stream>>>(x1, h_f32, c_mlp, out);
}